// Round 1
// baseline (456.483 us; speedup 1.0000x reference)
//
#include <hip/hip_runtime.h>
#include <hip/hip_bf16.h>
#include <cstdint>
#include <cstddef>

#define S_LEN 2048
#define BATCHN 2
#define DMODEL 1024
#define NHEADS 16
#define DHEAD 64
#define DFF 4096
#define NTOK (S_LEN*BATCHN)   // 4096 tokens

typedef __bf16 bf16x8 __attribute__((ext_vector_type(8)));
typedef float f32x4 __attribute__((ext_vector_type(4)));
typedef __hip_bfloat16 bf16s;

__device__ static inline void gload_lds16(const void* g, void* l) {
  __builtin_amdgcn_global_load_lds((const __attribute__((address_space(1))) void*)g,
                                   (__attribute__((address_space(3))) void*)l,
                                   16, 0, 0);
}

// ---------------- pack kernels ----------------

// transpose+convert: in f32 [K][N] row-major -> out bf16 [N][K] row-major
__global__ __launch_bounds__(256) void transpose_convert(const float* __restrict__ in,
                                                         bf16s* __restrict__ out,
                                                         int K, int N) {
  __shared__ float tile[32][33];
  const int tx = threadIdx.x & 31;
  const int ty = threadIdx.x >> 5;          // 0..7
  const int bx = blockIdx.x * 32;           // N dim
  const int by = blockIdx.y * 32;           // K dim
#pragma unroll
  for (int i = 0; i < 32; i += 8)
    tile[ty + i][tx] = in[(size_t)(by + ty + i) * N + bx + tx];
  __syncthreads();
#pragma unroll
  for (int i = 0; i < 32; i += 8)
    out[(size_t)(bx + ty + i) * K + by + tx] = __float2bfloat16(tile[tx][ty + i]);
}

__global__ __launch_bounds__(256) void cvt_bf16_kernel(const float* __restrict__ in,
                                                       bf16s* __restrict__ out, int n4) {
  int i = blockIdx.x * 256 + threadIdx.x;
  if (i < n4) {
    float4 v = ((const float4*)in)[i];
    union { bf16s h[4]; uint2 u; } pk;
    pk.h[0] = __float2bfloat16(v.x); pk.h[1] = __float2bfloat16(v.y);
    pk.h[2] = __float2bfloat16(v.z); pk.h[3] = __float2bfloat16(v.w);
    ((uint2*)out)[i] = pk.u;
  }
}

__global__ __launch_bounds__(256) void bias_concat_kernel(const float* __restrict__ bq,
                                                          const float* __restrict__ bk,
                                                          const float* __restrict__ bv,
                                                          float* __restrict__ bqkv) {
  int i = blockIdx.x * 256 + threadIdx.x;
  if (i < 3 * DMODEL) {
    float v = (i < DMODEL) ? bq[i] : (i < 2 * DMODEL ? bk[i - DMODEL] : bv[i - 2 * DMODEL]);
    bqkv[i] = v;
  }
}

// ---------------- GEMM ----------------
// C[M,N] = A[M,K](bf16) @ Bt[N,K]^T(bf16), tile 128x128, BK=64, 4 waves (2x2 of 64x64),
// 2-phase double-buffered LDS via global_load_lds(16B) with XOR-swizzled source.
// EPI: 0 = QKV scatter (+bias, Q*0.125)   1 = f32 out (+bias +residF)
//      2 = bf16 out (+bias, exact GELU)   3 = f32 out (+bias +residB bf16)
template<int EPI>
__global__ __launch_bounds__(256, 2)
void gemm_kernel(const bf16s* __restrict__ A, const bf16s* __restrict__ Bt,
                 int M, int N, int K,
                 const float* __restrict__ bias,
                 const float* __restrict__ residF,
                 const bf16s* __restrict__ residB,
                 float* __restrict__ outF, bf16s* __restrict__ outB,
                 bf16s* __restrict__ Qb, bf16s* __restrict__ Kb, bf16s* __restrict__ Vtb)
{
  __shared__ bf16s smem[2][2 * 128 * 64];   // per buf: A 16KB | B 16KB
  const int tid = threadIdx.x;
  const int l = tid & 63;
  const int w = tid >> 6;
  const int m0 = blockIdx.y * 128;
  const int n0 = blockIdx.x * 128;
  const int lr = l & 15, lg = l >> 4;

  f32x4 acc[4][4] = {};

  auto stageAB = [&](int buf, int kt) {
#pragma unroll
    for (int it = 0; it < 4; ++it) {
      int c = it * 4 + w;                       // 16 wave-chunks of 1KB each region
      int off = c * 1024 + l * 16;              // byte offset in region
      int row = off >> 7;                       // /128B per row (64 bf16)
      int kb = (off & 127) ^ ((row & 7) << 4);  // inverse-swizzle source
      const char* srcA = (const char*)A + ((size_t)(m0 + row) * K + kt) * 2 + kb;
      gload_lds16(srcA, (char*)&smem[buf][0] + c * 1024);
      const char* srcB = (const char*)Bt + ((size_t)(n0 + row) * K + kt) * 2 + kb;
      gload_lds16(srcB, (char*)&smem[buf][0] + 16384 + c * 1024);
    }
  };

  auto compute = [&](int buf) {
    const char* base = (const char*)&smem[buf][0];
    const int wm = (w >> 1) * 64, wn = (w & 1) * 64;
#pragma unroll
    for (int kk = 0; kk < 2; ++kk) {
      bf16x8 af[4], bfr[4];
#pragma unroll
      for (int mi = 0; mi < 4; ++mi) {
        int row = wm + mi * 16 + lr;
        int kb = (kk * 64 + lg * 16) ^ ((row & 7) << 4);
        af[mi] = *(const bf16x8*)(base + row * 128 + kb);
      }
#pragma unroll
      for (int ni = 0; ni < 4; ++ni) {
        int row = wn + ni * 16 + lr;
        int kb = (kk * 64 + lg * 16) ^ ((row & 7) << 4);
        bfr[ni] = *(const bf16x8*)(base + 16384 + row * 128 + kb);
      }
#pragma unroll
      for (int mi = 0; mi < 4; ++mi)
#pragma unroll
        for (int ni = 0; ni < 4; ++ni)
          acc[mi][ni] = __builtin_amdgcn_mfma_f32_16x16x32_bf16(af[mi], bfr[ni], acc[mi][ni], 0, 0, 0);
    }
  };

  const int nt = K / 64;
  stageAB(0, 0);
  __syncthreads();
  int cur = 0;
  for (int t = 0; t < nt - 1; ++t) {
    stageAB(cur ^ 1, (t + 1) * 64);
    compute(cur);
    __syncthreads();
    cur ^= 1;
  }
  compute(cur);

  // epilogue
  const int wm = (w >> 1) * 64, wn = (w & 1) * 64;
#pragma unroll
  for (int mi = 0; mi < 4; ++mi) {
#pragma unroll
    for (int ni = 0; ni < 4; ++ni) {
#pragma unroll
      for (int r = 0; r < 4; ++r) {
        int row = m0 + wm + mi * 16 + lg * 4 + r;
        int col = n0 + wn + ni * 16 + lr;
        float v = acc[mi][ni][r] + bias[col];
        if (EPI == 0) {
          int which = col >> 10;
          int h = (col & 1023) >> 6;
          int d = col & 63;
          int b = row & 1;          // token row t = s*B + b
          int s = row >> 1;
          if (which == 0)
            Qb[(((size_t)(b * NHEADS + h)) * S_LEN + s) * DHEAD + d] = __float2bfloat16(v * 0.125f);
          else if (which == 1)
            Kb[(((size_t)(b * NHEADS + h)) * S_LEN + s) * DHEAD + d] = __float2bfloat16(v);
          else
            Vtb[(((size_t)(b * NHEADS + h)) * DHEAD + d) * S_LEN + s] = __float2bfloat16(v);
        } else if (EPI == 1) {
          outF[(size_t)row * N + col] = v + residF[(size_t)row * N + col];
        } else if (EPI == 2) {
          float gv = 0.5f * v * (1.0f + erff(v * 0.70710678118654752f));
          outB[(size_t)row * N + col] = __float2bfloat16(gv);
        } else {
          outF[(size_t)row * N + col] = v + __bfloat162float(residB[(size_t)row * N + col]);
        }
      }
    }
  }
}

// ---------------- flash attention ----------------
// grid (32 qblocks, 16 heads, 2 batch), 256 threads (4 waves x 16 q-rows).
__global__ __launch_bounds__(256)
void attn_kernel(const bf16s* __restrict__ Qb, const bf16s* __restrict__ Kb,
                 const bf16s* __restrict__ Vtb, bf16s* __restrict__ ctx)
{
  __shared__ bf16s Ks[64 * 72];
  __shared__ bf16s Vs[64 * 72];
  __shared__ bf16s Ps[4 * 16 * 72];
  const int tid = threadIdx.x;
  const int l = tid & 63, w = tid >> 6;
  const int qb = blockIdx.x, h = blockIdx.y, b = blockIdx.z;
  const bf16s* Qh = Qb + ((size_t)(b * NHEADS + h)) * S_LEN * DHEAD;
  const bf16s* Kh = Kb + ((size_t)(b * NHEADS + h)) * S_LEN * DHEAD;
  const bf16s* Vh = Vtb + ((size_t)(b * NHEADS + h)) * DHEAD * S_LEN;
  const int lr = l & 15, lg = l >> 4;
  const int qrow = qb * 64 + w * 16 + lr;

  bf16x8 aq[2];
  aq[0] = *(const bf16x8*)(Qh + (size_t)qrow * DHEAD + lg * 8);
  aq[1] = *(const bf16x8*)(Qh + (size_t)qrow * DHEAD + 32 + lg * 8);

  f32x4 o[4] = {};
  float m_run[4] = {-1e30f, -1e30f, -1e30f, -1e30f};
  float l_run[4] = {0.f, 0.f, 0.f, 0.f};

  for (int kt = 0; kt < S_LEN / 64; ++kt) {
    const int s0 = kt * 64;
    // stage K tile [64][64] and V^T tile [64 d][64 s] (padded stride 72)
#pragma unroll
    for (int i = 0; i < 2; ++i) {
      int c = tid + i * 256;        // 0..511
      int row = c >> 3;
      int cb = (c & 7) * 16;        // byte within 128B row
      *(uint4*)((char*)Ks + row * 144 + cb) =
          *(const uint4*)((const char*)Kh + ((size_t)(s0 + row)) * 128 + cb);
      *(uint4*)((char*)Vs + row * 144 + cb) =
          *(const uint4*)((const char*)Vh + (size_t)row * S_LEN * 2 + s0 * 2 + cb);
    }
    __syncthreads();

    // scores: S[16q][64k] per wave
    f32x4 sc[4] = {};
#pragma unroll
    for (int kk = 0; kk < 2; ++kk) {
#pragma unroll
      for (int ni = 0; ni < 4; ++ni) {
        bf16x8 bk = *(const bf16x8*)((char*)Ks + (ni * 16 + lr) * 144 + kk * 64 + lg * 16);
        sc[ni] = __builtin_amdgcn_mfma_f32_16x16x32_bf16(aq[kk], bk, sc[ni], 0, 0, 0);
      }
    }

    // online softmax (rows r: q = lg*4+r; cols spread over lr and ni)
    float alpha[4];
#pragma unroll
    for (int r = 0; r < 4; ++r) {
      float mx = fmaxf(fmaxf(sc[0][r], sc[1][r]), fmaxf(sc[2][r], sc[3][r]));
      mx = fmaxf(mx, __shfl_xor(mx, 1));
      mx = fmaxf(mx, __shfl_xor(mx, 2));
      mx = fmaxf(mx, __shfl_xor(mx, 4));
      mx = fmaxf(mx, __shfl_xor(mx, 8));
      float nm = fmaxf(m_run[r], mx);
      alpha[r] = __expf(m_run[r] - nm);
      m_run[r] = nm;
      float rs = 0.f;
#pragma unroll
      for (int ni = 0; ni < 4; ++ni) {
        float p = __expf(sc[ni][r] - nm);
        sc[ni][r] = p;
        rs += p;
      }
      rs += __shfl_xor(rs, 1);
      rs += __shfl_xor(rs, 2);
      rs += __shfl_xor(rs, 4);
      rs += __shfl_xor(rs, 8);
      l_run[r] = l_run[r] * alpha[r] + rs;
#pragma unroll
      for (int di = 0; di < 4; ++di) o[di][r] *= alpha[r];
    }

    // P -> LDS (per-wave region), then read as A-fragments
    char* Pw = (char*)Ps + w * 16 * 144;
#pragma unroll
    for (int ni = 0; ni < 4; ++ni)
#pragma unroll
      for (int r = 0; r < 4; ++r)
        *(bf16s*)(Pw + (lg * 4 + r) * 144 + (ni * 16 + lr) * 2) = __float2bfloat16(sc[ni][r]);

#pragma unroll
    for (int kk = 0; kk < 2; ++kk) {
      bf16x8 ap = *(const bf16x8*)(Pw + lr * 144 + kk * 64 + lg * 16);
#pragma unroll
      for (int di = 0; di < 4; ++di) {
        bf16x8 bv = *(const bf16x8*)((char*)Vs + (di * 16 + lr) * 144 + kk * 64 + lg * 16);
        o[di] = __builtin_amdgcn_mfma_f32_16x16x32_bf16(ap, bv, o[di], 0, 0, 0);
      }
    }
    __syncthreads();
  }

  // write ctx [token][D]
#pragma unroll
  for (int r = 0; r < 4; ++r) {
    float inv = 1.0f / l_run[r];
    int s = qb * 64 + w * 16 + lg * 4 + r;
    int t = s * BATCHN + b;
#pragma unroll
    for (int di = 0; di < 4; ++di) {
      int d = h * DHEAD + di * 16 + lr;
      ctx[(size_t)t * DMODEL + d] = __float2bfloat16(o[di][r] * inv);
    }
  }
}

// ---------------- layernorm ----------------
template<int OUTBF>
__global__ __launch_bounds__(256)
void ln_kernel(const float* __restrict__ in, const float* __restrict__ g,
               const float* __restrict__ be, float* __restrict__ outF,
               bf16s* __restrict__ outB)
{
  const int row = blockIdx.x;
  const int tid = threadIdx.x;
  const float* x = in + (size_t)row * DMODEL;
  float4 v = ((const float4*)x)[tid];
  float s = v.x + v.y + v.z + v.w;
  float s2 = v.x * v.x + v.y * v.y + v.z * v.z + v.w * v.w;
#pragma unroll
  for (int m = 1; m < 64; m <<= 1) { s += __shfl_xor(s, m); s2 += __shfl_xor(s2, m); }
  __shared__ float sm[8];
  const int wv = tid >> 6, l = tid & 63;
  if (l == 0) { sm[wv] = s; sm[4 + wv] = s2; }
  __syncthreads();
  s = sm[0] + sm[1] + sm[2] + sm[3];
  s2 = sm[4] + sm[5] + sm[6] + sm[7];
  float mean = s * (1.0f / DMODEL);
  float var = s2 * (1.0f / DMODEL) - mean * mean;
  float rstd = rsqrtf(var + 1e-5f);
  float4 gv = ((const float4*)g)[tid];
  float4 bv = ((const float4*)be)[tid];
  float o0 = (v.x - mean) * rstd * gv.x + bv.x;
  float o1 = (v.y - mean) * rstd * gv.y + bv.y;
  float o2 = (v.z - mean) * rstd * gv.z + bv.z;
  float o3 = (v.w - mean) * rstd * gv.w + bv.w;
  if (OUTBF) {
    union { bf16s h[4]; uint2 u; } pk;
    pk.h[0] = __float2bfloat16(o0); pk.h[1] = __float2bfloat16(o1);
    pk.h[2] = __float2bfloat16(o2); pk.h[3] = __float2bfloat16(o3);
    ((uint2*)(outB + (size_t)row * DMODEL))[tid] = pk.u;
  } else {
    float4 ov = {o0, o1, o2, o3};
    ((float4*)(outF + (size_t)row * DMODEL))[tid] = ov;
  }
}

// ---------------- launch ----------------
extern "C" void kernel_launch(void* const* d_in, const int* in_sizes, int n_in,
                              void* d_out, int out_size, void* d_ws, size_t ws_size,
                              hipStream_t stream) {
  const float* x  = (const float*)d_in[0];
  const float* Wq = (const float*)d_in[1];
  const float* bq = (const float*)d_in[2];
  const float* Wk = (const float*)d_in[3];
  const float* bk = (const float*)d_in[4];
  const float* Wv = (const float*)d_in[5];
  const float* bv = (const float*)d_in[6];
  const float* Wo = (const float*)d_in[7];
  const float* bo = (const float*)d_in[8];
  const float* W1 = (const float*)d_in[9];
  const float* b1 = (const float*)d_in[10];
  const float* W2 = (const float*)d_in[11];
  const float* b2 = (const float*)d_in[12];
  const float* g1 = (const float*)d_in[13];
  const float* be1 = (const float*)d_in[14];
  const float* g2 = (const float*)d_in[15];
  const float* be2 = (const float*)d_in[16];

  char* ws = (char*)d_ws;
  size_t off = 0;
  auto alloc = [&](size_t bytes) -> void* {
    void* p = ws + off;
    off += (bytes + 255) & ~(size_t)255;
    return p;
  };
  bf16s* Wqkv_t = (bf16s*)alloc((size_t)3 * DMODEL * DMODEL * 2);
  bf16s* Wo_t   = (bf16s*)alloc((size_t)DMODEL * DMODEL * 2);
  bf16s* W1_t   = (bf16s*)alloc((size_t)DFF * DMODEL * 2);
  bf16s* W2_t   = (bf16s*)alloc((size_t)DMODEL * DFF * 2);
  float* bqkv   = (float*)alloc((size_t)3 * DMODEL * 4);
  bf16s* Xb     = (bf16s*)alloc((size_t)NTOK * DMODEL * 2);
  bf16s* Qb     = (bf16s*)alloc((size_t)NTOK * DMODEL * 2);
  bf16s* Kb     = (bf16s*)alloc((size_t)NTOK * DMODEL * 2);
  bf16s* Vtb    = (bf16s*)alloc((size_t)NTOK * DMODEL * 2);
  bf16s* ctx    = (bf16s*)alloc((size_t)NTOK * DMODEL * 2);
  float* s1     = (float*)alloc((size_t)NTOK * DMODEL * 4);   // pre-LN1 sum; reused as z
  bf16s* y1     = (bf16s*)alloc((size_t)NTOK * DMODEL * 2);
  bf16s* Hb     = (bf16s*)alloc((size_t)NTOK * DFF * 2);
  if (off > ws_size) return;  // workspace too small: fail loudly via wrong output

  // pack
  transpose_convert<<<dim3(DMODEL / 32, DMODEL / 32), 256, 0, stream>>>(Wq, Wqkv_t, DMODEL, DMODEL);
  transpose_convert<<<dim3(DMODEL / 32, DMODEL / 32), 256, 0, stream>>>(Wk, Wqkv_t + (size_t)DMODEL * DMODEL, DMODEL, DMODEL);
  transpose_convert<<<dim3(DMODEL / 32, DMODEL / 32), 256, 0, stream>>>(Wv, Wqkv_t + (size_t)2 * DMODEL * DMODEL, DMODEL, DMODEL);
  transpose_convert<<<dim3(DMODEL / 32, DMODEL / 32), 256, 0, stream>>>(Wo, Wo_t, DMODEL, DMODEL);
  transpose_convert<<<dim3(DFF / 32, DMODEL / 32), 256, 0, stream>>>(W1, W1_t, DMODEL, DFF);
  transpose_convert<<<dim3(DMODEL / 32, DFF / 32), 256, 0, stream>>>(W2, W2_t, DFF, DMODEL);
  bias_concat_kernel<<<12, 256, 0, stream>>>(bq, bk, bv, bqkv);
  cvt_bf16_kernel<<<(NTOK * DMODEL / 4 + 255) / 256, 256, 0, stream>>>(x, Xb, NTOK * DMODEL / 4);

  // QKV projection (fused) with scatter epilogue
  gemm_kernel<0><<<dim3(3 * DMODEL / 128, NTOK / 128), 256, 0, stream>>>(
      Xb, Wqkv_t, NTOK, 3 * DMODEL, DMODEL, bqkv, nullptr, nullptr, nullptr, nullptr, Qb, Kb, Vtb);

  // attention
  attn_kernel<<<dim3(S_LEN / 64, NHEADS, BATCHN), 256, 0, stream>>>(Qb, Kb, Vtb, ctx);

  // output projection + residual -> s1 (f32)
  gemm_kernel<1><<<dim3(DMODEL / 128, NTOK / 128), 256, 0, stream>>>(
      ctx, Wo_t, NTOK, DMODEL, DMODEL, bo, x, nullptr, s1, nullptr, nullptr, nullptr, nullptr);
  // LN1 -> y1 (bf16)
  ln_kernel<1><<<NTOK, 256, 0, stream>>>(s1, g1, be1, nullptr, y1);
  // FF1 + GELU -> Hb (bf16)
  gemm_kernel<2><<<dim3(DFF / 128, NTOK / 128), 256, 0, stream>>>(
      y1, W1_t, NTOK, DFF, DMODEL, b1, nullptr, nullptr, nullptr, Hb, nullptr, nullptr, nullptr);
  // FF2 + residual(y1) -> s1 (f32, reuse)
  gemm_kernel<3><<<dim3(DMODEL / 128, NTOK / 128), 256, 0, stream>>>(
      Hb, W2_t, NTOK, DMODEL, DFF, b2, nullptr, y1, s1, nullptr, nullptr, nullptr, nullptr);
  // LN2 -> out (f32)
  ln_kernel<0><<<NTOK, 256, 0, stream>>>(s1, g2, be2, (float*)d_out, nullptr);
}

// Round 2
// 396.761 us; speedup vs baseline: 1.1505x; 1.1505x over previous
//
#include <hip/hip_runtime.h>
#include <hip/hip_bf16.h>
#include <cstdint>
#include <cstddef>

#define S_LEN 2048
#define BATCHN 2
#define DMODEL 1024
#define NHEADS 16
#define DHEAD 64
#define DFF 4096
#define NTOK (S_LEN*BATCHN)   // 4096 tokens

typedef __bf16 bf16x8 __attribute__((ext_vector_type(8)));
typedef __bf16 bf16x4 __attribute__((ext_vector_type(4)));
typedef float f32x4 __attribute__((ext_vector_type(4)));
typedef __hip_bfloat16 bf16s;

// Q pre-scale: 1/sqrt(64) * log2(e)  (softmax runs in exp2 domain)
#define QSCALE 0.18033688011112042592f

__device__ static inline void gload_lds16(const void* g, void* l) {
  __builtin_amdgcn_global_load_lds((const __attribute__((address_space(1))) void*)g,
                                   (__attribute__((address_space(3))) void*)l,
                                   16, 0, 0);
}

// ---------------- pack kernels ----------------

__global__ __launch_bounds__(256) void transpose_convert(const float* __restrict__ in,
                                                         bf16s* __restrict__ out,
                                                         int K, int N) {
  __shared__ float tile[32][33];
  const int tx = threadIdx.x & 31;
  const int ty = threadIdx.x >> 5;
  const int bx = blockIdx.x * 32;
  const int by = blockIdx.y * 32;
#pragma unroll
  for (int i = 0; i < 32; i += 8)
    tile[ty + i][tx] = in[(size_t)(by + ty + i) * N + bx + tx];
  __syncthreads();
#pragma unroll
  for (int i = 0; i < 32; i += 8)
    out[(size_t)(bx + ty + i) * K + by + tx] = __float2bfloat16(tile[tx][ty + i]);
}

__global__ __launch_bounds__(256) void cvt_bf16_kernel(const float* __restrict__ in,
                                                       bf16s* __restrict__ out, int n4) {
  int i = blockIdx.x * 256 + threadIdx.x;
  if (i < n4) {
    float4 v = ((const float4*)in)[i];
    union { bf16s h[4]; uint2 u; } pk;
    pk.h[0] = __float2bfloat16(v.x); pk.h[1] = __float2bfloat16(v.y);
    pk.h[2] = __float2bfloat16(v.z); pk.h[3] = __float2bfloat16(v.w);
    ((uint2*)out)[i] = pk.u;
  }
}

__global__ __launch_bounds__(256) void bias_concat_kernel(const float* __restrict__ bq,
                                                          const float* __restrict__ bk,
                                                          const float* __restrict__ bv,
                                                          float* __restrict__ bqkv) {
  int i = blockIdx.x * 256 + threadIdx.x;
  if (i < 3 * DMODEL) {
    float v = (i < DMODEL) ? bq[i] : (i < 2 * DMODEL ? bk[i - DMODEL] : bv[i - 2 * DMODEL]);
    bqkv[i] = v;
  }
}

// ---------------- GEMM ----------------
template<int EPI>
__global__ __launch_bounds__(256, 2)
void gemm_kernel(const bf16s* __restrict__ A, const bf16s* __restrict__ Bt,
                 int M, int N, int K,
                 const float* __restrict__ bias,
                 const float* __restrict__ residF,
                 const bf16s* __restrict__ residB,
                 float* __restrict__ outF, bf16s* __restrict__ outB,
                 bf16s* __restrict__ Qb, bf16s* __restrict__ Kb, bf16s* __restrict__ Vtb)
{
  __shared__ bf16s smem[2][2 * 128 * 64];
  const int tid = threadIdx.x;
  const int l = tid & 63;
  const int w = tid >> 6;
  const int m0 = blockIdx.y * 128;
  const int n0 = blockIdx.x * 128;
  const int lr = l & 15, lg = l >> 4;

  f32x4 acc[4][4] = {};

  auto stageAB = [&](int buf, int kt) {
#pragma unroll
    for (int it = 0; it < 4; ++it) {
      int c = it * 4 + w;
      int off = c * 1024 + l * 16;
      int row = off >> 7;
      int kb = (off & 127) ^ ((row & 7) << 4);
      const char* srcA = (const char*)A + ((size_t)(m0 + row) * K + kt) * 2 + kb;
      gload_lds16(srcA, (char*)&smem[buf][0] + c * 1024);
      const char* srcB = (const char*)Bt + ((size_t)(n0 + row) * K + kt) * 2 + kb;
      gload_lds16(srcB, (char*)&smem[buf][0] + 16384 + c * 1024);
    }
  };

  auto compute = [&](int buf) {
    const char* base = (const char*)&smem[buf][0];
    const int wm = (w >> 1) * 64, wn = (w & 1) * 64;
#pragma unroll
    for (int kk = 0; kk < 2; ++kk) {
      bf16x8 af[4], bfr[4];
#pragma unroll
      for (int mi = 0; mi < 4; ++mi) {
        int row = wm + mi * 16 + lr;
        int kb = (kk * 64 + lg * 16) ^ ((row & 7) << 4);
        af[mi] = *(const bf16x8*)(base + row * 128 + kb);
      }
#pragma unroll
      for (int ni = 0; ni < 4; ++ni) {
        int row = wn + ni * 16 + lr;
        int kb = (kk * 64 + lg * 16) ^ ((row & 7) << 4);
        bfr[ni] = *(const bf16x8*)(base + 16384 + row * 128 + kb);
      }
#pragma unroll
      for (int mi = 0; mi < 4; ++mi)
#pragma unroll
        for (int ni = 0; ni < 4; ++ni)
          acc[mi][ni] = __builtin_amdgcn_mfma_f32_16x16x32_bf16(af[mi], bfr[ni], acc[mi][ni], 0, 0, 0);
    }
  };

  const int nt = K / 64;
  stageAB(0, 0);
  __syncthreads();
  int cur = 0;
  for (int t = 0; t < nt - 1; ++t) {
    stageAB(cur ^ 1, (t + 1) * 64);
    compute(cur);
    __syncthreads();
    cur ^= 1;
  }
  compute(cur);

  const int wm = (w >> 1) * 64, wn = (w & 1) * 64;
#pragma unroll
  for (int mi = 0; mi < 4; ++mi) {
#pragma unroll
    for (int ni = 0; ni < 4; ++ni) {
#pragma unroll
      for (int r = 0; r < 4; ++r) {
        int row = m0 + wm + mi * 16 + lg * 4 + r;
        int col = n0 + wn + ni * 16 + lr;
        float v = acc[mi][ni][r] + bias[col];
        if (EPI == 0) {
          int which = col >> 10;
          int h = (col & 1023) >> 6;
          int d = col & 63;
          int b = row & 1;
          int s = row >> 1;
          if (which == 0)
            Qb[(((size_t)(b * NHEADS + h)) * S_LEN + s) * DHEAD + d] = __float2bfloat16(v * QSCALE);
          else if (which == 1)
            Kb[(((size_t)(b * NHEADS + h)) * S_LEN + s) * DHEAD + d] = __float2bfloat16(v);
          else
            Vtb[(((size_t)(b * NHEADS + h)) * DHEAD + d) * S_LEN + s] = __float2bfloat16(v);
        } else if (EPI == 1) {
          outF[(size_t)row * N + col] = v + residF[(size_t)row * N + col];
        } else if (EPI == 2) {
          float gv = 0.5f * v * (1.0f + erff(v * 0.70710678118654752f));
          outB[(size_t)row * N + col] = __float2bfloat16(gv);
        } else {
          outF[(size_t)row * N + col] = v + __bfloat162float(residB[(size_t)row * N + col]);
        }
      }
    }
  }
}

// ---------------- flash attention (swapped-QK^T, 2 q-subtiles/wave) ----------------
// grid: 512 blocks (XCD-swizzled), 256 threads = 4 waves x 32 q-rows -> 128 q/block.
// KV tile = 64, double-buffered in LDS via global_load_lds + XOR swizzle.
// LDS: [buf0: K 8K | V 8K][buf1: K 8K | V 8K][P: 4 waves x 32 x 144B]
__global__ __launch_bounds__(256, 2)
void attn_kernel(const bf16s* __restrict__ Qb, const bf16s* __restrict__ Kb,
                 const bf16s* __restrict__ Vtb, bf16s* __restrict__ ctx)
{
  __shared__ __align__(1024) char lds[51200];
  const int tid = threadIdx.x;
  const int l = tid & 63, w = tid >> 6;
  const int lr = l & 15, lg = l >> 4;

  // XCD-chunked bijective swizzle: 512 = 8 * 64
  int lin = blockIdx.x;
  int wg = (lin & 7) * 64 + (lin >> 3);
  int qb = wg & 15;          // 16 q-blocks of 128
  int hb = wg >> 4;          // 0..31
  int h = hb & 15, b = hb >> 4;

  const char* Qg = (const char*)(Qb + ((size_t)(b * NHEADS + h)) * S_LEN * DHEAD);
  const char* Kg = (const char*)(Kb + ((size_t)(b * NHEADS + h)) * S_LEN * DHEAD);
  const char* Vg = (const char*)(Vtb + ((size_t)(b * NHEADS + h)) * DHEAD * S_LEN);

  // per-lane precomputed offsets
  const int swz = (lr & 7) << 4;
  const int aK0 = lr * 128 + ((lg * 16) ^ swz);          // frag addr, kk=0
  const int aK1 = lr * 128 + ((64 + lg * 16) ^ swz);     // frag addr, kk=1
  const int klane = (l >> 3) * 128  + (((l & 7) * 16) ^ ((l & 56) << 1));  // K stage src
  const int vlane = (l >> 3) * 4096 + (((l & 7) * 16) ^ ((l & 56) << 1));  // V stage src
  const int l16 = l * 16;
  char* Pw = lds + 32768 + w * 4608;       // 32 rows x 144B
  const int pwA = lr * 144 + lg * 8;       // P write lane addr
  const int prA = lr * 144 + lg * 16;      // P read  lane addr

  // Q fragments (B operand of swapped QK^T): lane holds Q[q0+qi*16+lr][kk*32+lg*8 ..]
  const int q0 = qb * 128 + w * 32;
  bf16x8 aq[2][2];
#pragma unroll
  for (int qi = 0; qi < 2; ++qi)
#pragma unroll
    for (int kk = 0; kk < 2; ++kk)
      aq[qi][kk] = *(const bf16x8*)(Qg + (size_t)(q0 + qi * 16 + lr) * 128 + kk * 64 + lg * 16);

  f32x4 o0[4] = {}, o1[4] = {};
  float m0 = -1e30f, m1 = -1e30f;
  float ls0 = 0.f, ls1 = 0.f;

  const int NT = S_LEN / 64;

  auto stage = [&](char* dK, int tile) {
    const char* kbg = Kg + (size_t)tile * 8192;
    const char* vbg = Vg + (size_t)tile * 128;
    char* dV = dK + 8192;
#pragma unroll
    for (int i = 0; i < 2; ++i) {
      int c = w * 2 + i;
      gload_lds16(kbg + c * 1024 + klane, dK + c * 1024 + l16);
      gload_lds16(vbg + (size_t)c * 32768 + vlane, dV + c * 1024 + l16);
    }
  };

  stage(lds, 0);
  asm volatile("s_waitcnt vmcnt(0)" ::: "memory");
  __builtin_amdgcn_s_barrier();

#define ATTN_ITER(BUF, t)                                                        \
  {                                                                              \
    int nxt = ((t) + 1 < NT) ? (t) + 1 : NT - 1;                                 \
    stage(lds + ((BUF) ^ 1) * 16384, nxt);                                       \
    const char* bK = lds + (BUF) * 16384;                                        \
    const char* bV = bK + 8192;                                                  \
    f32x4 st0[4], st1[4];                                                        \
    _Pragma("unroll")                                                            \
    for (int ni = 0; ni < 4; ++ni) {                                             \
      bf16x8 k0 = *(const bf16x8*)(bK + ni * 2048 + aK0);                        \
      bf16x8 k1 = *(const bf16x8*)(bK + ni * 2048 + aK1);                        \
      f32x4 z = {};                                                              \
      st0[ni] = __builtin_amdgcn_mfma_f32_16x16x32_bf16(k0, aq[0][0], z, 0, 0, 0);\
      st0[ni] = __builtin_amdgcn_mfma_f32_16x16x32_bf16(k1, aq[0][1], st0[ni], 0, 0, 0);\
      st1[ni] = __builtin_amdgcn_mfma_f32_16x16x32_bf16(k0, aq[1][0], z, 0, 0, 0);\
      st1[ni] = __builtin_amdgcn_mfma_f32_16x16x32_bf16(k1, aq[1][1], st1[ni], 0, 0, 0);\
    }                                                                            \
    f32x4 vm0 = st0[0], vm1 = st1[0];                                            \
    _Pragma("unroll")                                                            \
    for (int ni = 1; ni < 4; ++ni) {                                             \
      _Pragma("unroll")                                                          \
      for (int r = 0; r < 4; ++r) {                                              \
        vm0[r] = fmaxf(vm0[r], st0[ni][r]);                                      \
        vm1[r] = fmaxf(vm1[r], st1[ni][r]);                                      \
      }                                                                          \
    }                                                                            \
    float mx0 = fmaxf(fmaxf(vm0[0], vm0[1]), fmaxf(vm0[2], vm0[3]));             \
    float mx1 = fmaxf(fmaxf(vm1[0], vm1[1]), fmaxf(vm1[2], vm1[3]));             \
    mx0 = fmaxf(mx0, __shfl_xor(mx0, 16)); mx0 = fmaxf(mx0, __shfl_xor(mx0, 32));\
    mx1 = fmaxf(mx1, __shfl_xor(mx1, 16)); mx1 = fmaxf(mx1, __shfl_xor(mx1, 32));\
    if (!__all(mx0 <= m0 + 8.f && mx1 <= m1 + 8.f)) {                            \
      float nm0 = fmaxf(m0, mx0), nm1 = fmaxf(m1, mx1);                          \
      float al0 = exp2f(m0 - nm0), al1 = exp2f(m1 - nm1);                        \
      m0 = nm0; m1 = nm1; ls0 *= al0; ls1 *= al1;                                \
      _Pragma("unroll")                                                          \
      for (int r = 0; r < 4; ++r) {                                              \
        float s0r = __shfl(al0, lg * 4 + r);                                     \
        float s1r = __shfl(al1, lg * 4 + r);                                     \
        _Pragma("unroll")                                                        \
        for (int di = 0; di < 4; ++di) { o0[di][r] *= s0r; o1[di][r] *= s1r; }   \
      }                                                                          \
    }                                                                            \
    f32x4 ac0 = {}, ac1 = {};                                                    \
    _Pragma("unroll")                                                            \
    for (int ni = 0; ni < 4; ++ni) {                                             \
      _Pragma("unroll")                                                          \
      for (int r = 0; r < 4; ++r) {                                              \
        st0[ni][r] = exp2f(st0[ni][r] - m0);                                     \
        st1[ni][r] = exp2f(st1[ni][r] - m1);                                     \
      }                                                                          \
      ac0 += st0[ni]; ac1 += st1[ni];                                            \
    }                                                                            \
    ls0 += ac0[0] + ac0[1] + ac0[2] + ac0[3];                                    \
    ls1 += ac1[0] + ac1[1] + ac1[2] + ac1[3];                                    \
    _Pragma("unroll")                                                            \
    for (int ni = 0; ni < 4; ++ni) {                                             \
      bf16x4 p0, p1;                                                             \
      _Pragma("unroll")                                                          \
      for (int j = 0; j < 4; ++j) { p0[j] = (__bf16)st0[ni][j]; p1[j] = (__bf16)st1[ni][j]; }\
      *(bf16x4*)(Pw + pwA + ni * 32) = p0;                                       \
      *(bf16x4*)(Pw + 2304 + pwA + ni * 32) = p1;                                \
    }                                                                            \
    _Pragma("unroll")                                                            \
    for (int kk = 0; kk < 2; ++kk) {                                             \
      bf16x8 ap0 = *(const bf16x8*)(Pw + prA + kk * 64);                         \
      bf16x8 ap1 = *(const bf16x8*)(Pw + 2304 + prA + kk * 64);                  \
      const int av = kk ? aK1 : aK0;                                             \
      _Pragma("unroll")                                                          \
      for (int di = 0; di < 4; ++di) {                                           \
        bf16x8 vv = *(const bf16x8*)(bV + di * 2048 + av);                       \
        o0[di] = __builtin_amdgcn_mfma_f32_16x16x32_bf16(ap0, vv, o0[di], 0, 0, 0);\
        o1[di] = __builtin_amdgcn_mfma_f32_16x16x32_bf16(ap1, vv, o1[di], 0, 0, 0);\
      }                                                                          \
    }                                                                            \
    asm volatile("s_waitcnt vmcnt(0)" ::: "memory");                             \
    __builtin_amdgcn_s_barrier();                                                \
  }

  for (int t = 0; t < NT; t += 2) {
    ATTN_ITER(0, t);
    ATTN_ITER(1, t + 1);
  }
#undef ATTN_ITER

  // epilogue: normalize + write ctx[token][D]
#pragma unroll
  for (int qi = 0; qi < 2; ++qi) {
    float ls = qi ? ls1 : ls0;
    ls += __shfl_xor(ls, 16);
    ls += __shfl_xor(ls, 32);
    float inv = 1.0f / ls;
#pragma unroll
    for (int r = 0; r < 4; ++r) {
      float invr = __shfl(inv, lg * 4 + r);
      int srow = q0 + qi * 16 + lg * 4 + r;
      int tkn = srow * BATCHN + b;
#pragma unroll
      for (int di = 0; di < 4; ++di) {
        int d = h * DHEAD + di * 16 + lr;
        float v = (qi ? o1[di][r] : o0[di][r]) * invr;
        ctx[(size_t)tkn * DMODEL + d] = __float2bfloat16(v);
      }
    }
  }
}

// ---------------- layernorm ----------------
template<int OUTBF>
__global__ __launch_bounds__(256)
void ln_kernel(const float* __restrict__ in, const float* __restrict__ g,
               const float* __restrict__ be, float* __restrict__ outF,
               bf16s* __restrict__ outB)
{
  const int row = blockIdx.x;
  const int tid = threadIdx.x;
  const float* x = in + (size_t)row * DMODEL;
  float4 v = ((const float4*)x)[tid];
  float s = v.x + v.y + v.z + v.w;
  float s2 = v.x * v.x + v.y * v.y + v.z * v.z + v.w * v.w;
#pragma unroll
  for (int m = 1; m < 64; m <<= 1) { s += __shfl_xor(s, m); s2 += __shfl_xor(s2, m); }
  __shared__ float sm[8];
  const int wv = tid >> 6, l = tid & 63;
  if (l == 0) { sm[wv] = s; sm[4 + wv] = s2; }
  __syncthreads();
  s = sm[0] + sm[1] + sm[2] + sm[3];
  s2 = sm[4] + sm[5] + sm[6] + sm[7];
  float mean = s * (1.0f / DMODEL);
  float var = s2 * (1.0f / DMODEL) - mean * mean;
  float rstd = rsqrtf(var + 1e-5f);
  float4 gv = ((const float4*)g)[tid];
  float4 bv = ((const float4*)be)[tid];
  float o0 = (v.x - mean) * rstd * gv.x + bv.x;
  float o1 = (v.y - mean) * rstd * gv.y + bv.y;
  float o2 = (v.z - mean) * rstd * gv.z + bv.z;
  float o3 = (v.w - mean) * rstd * gv.w + bv.w;
  if (OUTBF) {
    union { bf16s h[4]; uint2 u; } pk;
    pk.h[0] = __float2bfloat16(o0); pk.h[1] = __float2bfloat16(o1);
    pk.h[2] = __float2bfloat16(o2); pk.h[3] = __float2bfloat16(o3);
    ((uint2*)(outB + (size_t)row * DMODEL))[tid] = pk.u;
  } else {
    float4 ov = {o0, o1, o2, o3};
    ((float4*)(outF + (size_t)row * DMODEL))[tid] = ov;
  }
}

// ---------------- launch ----------------
extern "C" void kernel_launch(void* const* d_in, const int* in_sizes, int n_in,
                              void* d_out, int out_size, void* d_ws, size_t ws_size,
                              hipStream_t stream) {
  const float* x  = (const float*)d_in[0];
  const float* Wq = (const float*)d_in[1];
  const float* bq = (const float*)d_in[2];
  const float* Wk = (const float*)d_in[3];
  const float* bk = (const float*)d_in[4];
  const float* Wv = (const float*)d_in[5];
  const float* bv = (const float*)d_in[6];
  const float* Wo = (const float*)d_in[7];
  const float* bo = (const float*)d_in[8];
  const float* W1 = (const float*)d_in[9];
  const float* b1 = (const float*)d_in[10];
  const float* W2 = (const float*)d_in[11];
  const float* b2 = (const float*)d_in[12];
  const float* g1 = (const float*)d_in[13];
  const float* be1 = (const float*)d_in[14];
  const float* g2 = (const float*)d_in[15];
  const float* be2 = (const float*)d_in[16];

  char* ws = (char*)d_ws;
  size_t off = 0;
  auto alloc = [&](size_t bytes) -> void* {
    void* p = ws + off;
    off += (bytes + 255) & ~(size_t)255;
    return p;
  };
  bf16s* Wqkv_t = (bf16s*)alloc((size_t)3 * DMODEL * DMODEL * 2);
  bf16s* Wo_t   = (bf16s*)alloc((size_t)DMODEL * DMODEL * 2);
  bf16s* W1_t   = (bf16s*)alloc((size_t)DFF * DMODEL * 2);
  bf16s* W2_t   = (bf16s*)alloc((size_t)DMODEL * DFF * 2);
  float* bqkv   = (float*)alloc((size_t)3 * DMODEL * 4);
  bf16s* Xb     = (bf16s*)alloc((size_t)NTOK * DMODEL * 2);
  bf16s* Qb     = (bf16s*)alloc((size_t)NTOK * DMODEL * 2);
  bf16s* Kb     = (bf16s*)alloc((size_t)NTOK * DMODEL * 2);
  bf16s* Vtb    = (bf16s*)alloc((size_t)NTOK * DMODEL * 2);
  bf16s* ctx    = (bf16s*)alloc((size_t)NTOK * DMODEL * 2);
  float* s1     = (float*)alloc((size_t)NTOK * DMODEL * 4);
  bf16s* y1     = (bf16s*)alloc((size_t)NTOK * DMODEL * 2);
  bf16s* Hb     = (bf16s*)alloc((size_t)NTOK * DFF * 2);
  if (off > ws_size) return;

  transpose_convert<<<dim3(DMODEL / 32, DMODEL / 32), 256, 0, stream>>>(Wq, Wqkv_t, DMODEL, DMODEL);
  transpose_convert<<<dim3(DMODEL / 32, DMODEL / 32), 256, 0, stream>>>(Wk, Wqkv_t + (size_t)DMODEL * DMODEL, DMODEL, DMODEL);
  transpose_convert<<<dim3(DMODEL / 32, DMODEL / 32), 256, 0, stream>>>(Wv, Wqkv_t + (size_t)2 * DMODEL * DMODEL, DMODEL, DMODEL);
  transpose_convert<<<dim3(DMODEL / 32, DMODEL / 32), 256, 0, stream>>>(Wo, Wo_t, DMODEL, DMODEL);
  transpose_convert<<<dim3(DFF / 32, DMODEL / 32), 256, 0, stream>>>(W1, W1_t, DMODEL, DFF);
  transpose_convert<<<dim3(DMODEL / 32, DFF / 32), 256, 0, stream>>>(W2, W2_t, DFF, DMODEL);
  bias_concat_kernel<<<12, 256, 0, stream>>>(bq, bk, bv, bqkv);
  cvt_bf16_kernel<<<(NTOK * DMODEL / 4 + 255) / 256, 256, 0, stream>>>(x, Xb, NTOK * DMODEL / 4);

  gemm_kernel<0><<<dim3(3 * DMODEL / 128, NTOK / 128), 256, 0, stream>>>(
      Xb, Wqkv_t, NTOK, 3 * DMODEL, DMODEL, bqkv, nullptr, nullptr, nullptr, nullptr, Qb, Kb, Vtb);

  attn_kernel<<<512, 256, 0, stream>>>(Qb, Kb, Vtb, ctx);

  gemm_kernel<1><<<dim3(DMODEL / 128, NTOK / 128), 256, 0, stream>>>(
      ctx, Wo_t, NTOK, DMODEL, DMODEL, bo, x, nullptr, s1, nullptr, nullptr, nullptr, nullptr);
  ln_kernel<1><<<NTOK, 256, 0, stream>>>(s1, g1, be1, nullptr, y1);
  gemm_kernel<2><<<dim3(DFF / 128, NTOK / 128), 256, 0, stream>>>(
      y1, W1_t, NTOK, DFF, DMODEL, b1, nullptr, nullptr, nullptr, Hb, nullptr, nullptr, nullptr);
  gemm_kernel<3><<<dim3(DMODEL / 128, NTOK / 128), 256, 0, stream>>>(
      Hb, W2_t, NTOK, DMODEL, DFF, b2, nullptr, y1, s1, nullptr, nullptr, nullptr, nullptr);
  ln_kernel<0><<<NTOK, 256, 0, stream>>>(s1, g2, be2, (float*)d_out, nullptr);
}